// Round 12
// baseline (609.654 us; speedup 1.0000x reference)
//
#include <hip/hip_runtime.h>

#define B_N 16384
#define D_K 512
#define C_N 1000
#define CP 1024
#define M_N 8
#define GAP_EPS 1e-3f

typedef __attribute__((ext_vector_type(8))) _Float16 f16x8;
typedef __attribute__((ext_vector_type(4))) float f32x4;

typedef const __attribute__((address_space(1))) unsigned int* gptr_t;
typedef __attribute__((address_space(3))) unsigned int* lptr_t;

__device__ __forceinline__ void gload16(const void* g, void* l) {
    __builtin_amdgcn_global_load_lds((gptr_t)g, (lptr_t)l, 16, 0, 0);
}

#define BAR()        asm volatile("s_barrier" ::: "memory")
#define WAIT_LGKM0() asm volatile("s_waitcnt lgkmcnt(0)" ::: "memory")
#define WAIT_VM1()   asm volatile("s_waitcnt vmcnt(1)" ::: "memory")
#define WAIT_VM0()   asm volatile("s_waitcnt vmcnt(0)" ::: "memory")
#define SCHEDB()     __builtin_amdgcn_sched_barrier(0)

__device__ __forceinline__ unsigned short h16(float f) {
    _Float16 h = (_Float16)f;   // v_cvt_f16_f32, RTN
    return *(unsigned short*)&h;
}

// ---------------- fused conversion kernel ----------------
// blocks [0,8192): x fp32 -> fp16 ; blocks [8192,9216): W -> WT16 transposed

__global__ __launch_bounds__(256) void ve_conv(const float* __restrict__ x,
        const float* __restrict__ W, unsigned short* __restrict__ xf,
        unsigned short* __restrict__ wt, unsigned int* __restrict__ cnts) {
    const int tid = threadIdx.x;
    if (blockIdx.x < 8192) {
        int i = blockIdx.x * 256 + tid;
        if (blockIdx.x == 0 && tid < M_N) cnts[tid] = 0u;
        float4 v = reinterpret_cast<const float4*>(x)[i];
        ushort4 h;
        h.x = h16(v.x); h.y = h16(v.y); h.z = h16(v.z); h.w = h16(v.w);
        reinterpret_cast<ushort4*>(xf)[i] = h;
    } else {
        __shared__ float t[64][65];
        const int b = blockIdx.x - 8192;
        const int c0 = (b & 15) * 64, k0 = ((b >> 4) & 7) * 64, m = b >> 7;
#pragma unroll
        for (int p = 0; p < 16; ++p) {
            int idx = p * 256 + tid;
            int kk = idx >> 6, cc = idx & 63;
            int c = c0 + cc;
            t[kk][cc] = (c < C_N) ? W[((size_t)m * D_K + k0 + kk) * C_N + c] : 0.f;
        }
        __syncthreads();
#pragma unroll
        for (int p = 0; p < 4; ++p) {
            int idx = p * 256 + tid;
            int cc = idx >> 4, kq = idx & 15;
            ushort4 h;
            h.x = h16(t[kq * 4 + 0][cc]); h.y = h16(t[kq * 4 + 1][cc]);
            h.z = h16(t[kq * 4 + 2][cc]); h.w = h16(t[kq * 4 + 3][cc]);
            size_t o = ((size_t)m * CP + c0 + cc) * D_K + k0 + kq * 4;
            *reinterpret_cast<ushort4*>(wt + o) = h;
        }
    }
}

// ---------------- B-resident fp16 MFMA GEMM ----------------
// Block = 128 rows x 128 cols, 512 threads (8 waves = 2r x 4c, per-wave 64x32).
// LDS: Bp = FULL B panel (16 x 8KB swizzled subtiles, staged once in prologue),
// Ab = A double-buffer (2 x 8KB). K-loop stages only A, 1-deep prefetch,
// counted vmcnt(1) - no full drains. Subtile layout = round-9-verified
// paired-row XOR swizzle; inverse pre-applied on the global source.
// XCD swizzle: model mb pinned to one XCD so its B panels stay L2-resident.

__global__ __launch_bounds__(512, 1) void ve_gemm16e(
        const unsigned short* __restrict__ Xf, const unsigned short* __restrict__ WT,
        const float* __restrict__ bias, float4* __restrict__ part) {
    __shared__ unsigned short Bp[65536];   // 128 KB: 16 subtiles of [128c x 32k]
    __shared__ unsigned short Ab[8192];    // 16 KB: 2 bufs of [128r x 32k]

    const int tid = threadIdx.x;
    const int l = tid & 63, w = tid >> 6;
    const int wr = w >> 2, wc = w & 3;     // 2r x 4c waves; per-wave C = 64x32
    const int l15 = l & 15, kg = l >> 4;

    const int bid = blockIdx.x;
    const int f = ((bid & 7) << 10) | (bid >> 3);   // bijective XCD swizzle
    const int rt = f & 127, ct = (f >> 7) & 7, mb = f >> 10;
    const int r0 = rt * 128, c0 = ct * 128;

    // staging lane constants (verified inverse swizzle)
    const int lhi = l >> 3, llo = l & 7;
    const int s3g = llo ^ lhi;
    const int srow16 = (lhi << 1) | (s3g >> 2);
    const int kgs = (s3g & 3) * 8;          // shorts

    const unsigned short* gA = Xf + (size_t)(r0 + w * 16 + srow16) * D_K + kgs;
    const unsigned short* gB = WT + (size_t)(mb * CP + c0 + w * 16 + srow16) * D_K + kgs;
    unsigned short* dA = Ab + tid * 8;      // + buf*4096
    unsigned short* dB = Bp + tid * 8;      // + kt*4096

    // fragment read byte-offsets (loop-invariant within a subtile)
    auto ldsoff = [&](int row, int kc) {
        return (row >> 1) * 64 + (((((row & 1) << 2) | kc) ^ ((row >> 1) & 7)) * 8);
    };
    unsigned aOff[4], bOff[2];
#pragma unroll
    for (int i = 0; i < 4; ++i) aOff[i] = 2u * ldsoff(wr * 64 + i * 16 + l15, kg);
#pragma unroll
    for (int j = 0; j < 2; ++j) bOff[j] = 2u * ldsoff(wc * 32 + j * 16 + l15, kg);

    // ---- prologue: stage whole B panel + A(0), A(1) ----
#pragma unroll
    for (int kt = 0; kt < 16; ++kt)
        gload16(gB + kt * 32, dB + kt * 4096);
    gload16(gA,      dA);            // A(0) -> buf 0
    gload16(gA + 32, dA + 4096);     // A(1) -> buf 1
    WAIT_VM1();                      // B + A(0) landed; A(1) in flight
    BAR();

    f32x4 acc[4][2];
#pragma unroll
    for (int i = 0; i < 4; ++i)
#pragma unroll
        for (int j = 0; j < 2; ++j) acc[i][j] = (f32x4){0.f, 0.f, 0.f, 0.f};

#pragma unroll 1
    for (int t = 0; t < 16; ++t) {
        const char* aBase = (const char*)Ab + (t & 1) * 8192;
        const char* bBase = (const char*)Bp + t * 8192;
        f16x8 af[4], bf[2];
#pragma unroll
        for (int i = 0; i < 4; ++i) af[i] = *reinterpret_cast<const f16x8*>(aBase + aOff[i]);
#pragma unroll
        for (int j = 0; j < 2; ++j) bf[j] = *reinterpret_cast<const f16x8*>(bBase + bOff[j]);
#pragma unroll
        for (int i = 0; i < 4; ++i)
#pragma unroll
            for (int j = 0; j < 2; ++j)
                acc[i][j] = __builtin_amdgcn_mfma_f32_16x16x32_f16(af[i], bf[j], acc[i][j], 0, 0, 0);

        WAIT_LGKM0(); SCHEDB();
        BAR();   // all waves done reading Ab[t&1]
        if (t < 14) {
            gload16(gA + (t + 2) * 32, dA + (t & 1) * 4096);  // A(t+2) -> freed buf
            WAIT_VM1();     // A(t+1) landed (only A(t+2) newer)
        } else if (t == 14) {
            WAIT_VM0();     // A(15) landed
        }
        BAR();   // A(t+1) visible block-wide
    }

    // ---------------- epilogue: bias + cheap running top-2 ----------------
    WAIT_LGKM0();
    BAR();
    float4 (*wtop)[4] = reinterpret_cast<float4(*)[4]>(Ab);   // overlays dead Ab

    float bv[2]; int cg[2];
#pragma unroll
    for (int j = 0; j < 2; ++j) {
        int c = c0 + wc * 32 + j * 16 + l15;
        cg[j] = c;
        bv[j] = (c < C_N) ? bias[mb * C_N + c] : -1e30f;
    }
#pragma unroll
    for (int i = 0; i < 4; ++i) {
#pragma unroll
        for (int reg = 0; reg < 4; ++reg) {
            float v1 = acc[i][0][reg] + bv[0]; int i1 = cg[0];
            float v  = acc[i][1][reg] + bv[1];
            float v2 = fminf(v, v1);
            i1 = (v > v1) ? cg[1] : i1;
            v1 = fmaxf(v1, v);
#pragma unroll
            for (int mask = 1; mask < 16; mask <<= 1) {
                float ov1 = __shfl_xor(v1, mask);
                int   oi1 = __shfl_xor(i1, mask);
                float ov2 = __shfl_xor(v2, mask);
                float mn = fminf(v1, ov1);
                v2 = fmaxf(fmaxf(v2, ov2), mn);
                i1 = (ov1 > v1) ? oi1 : i1;
                v1 = fmaxf(v1, ov1);
            }
            if (l15 == 0) {
                int row = wr * 64 + i * 16 + (l >> 4) * 4 + reg;
                wtop[row][wc] = make_float4(v1, __int_as_float(i1), v2, 0.f);
            }
        }
    }
    BAR();
    if (tid < 128) {
        float4 o = wtop[tid][0];
        float v1 = o.x; int i1 = __float_as_int(o.y); float v2 = o.z;
#pragma unroll
        for (int s = 1; s < 4; ++s) {
            float4 q = wtop[tid][s];
            if (q.x > v1) {
                v2 = fmaxf(v1, fmaxf(q.z, v2));
                v1 = q.x; i1 = __float_as_int(q.y);
            } else {
                v2 = fmaxf(v2, q.x);
            }
        }
        part[((size_t)mb * B_N + r0 + tid) * 8 + ct] =
            make_float4(v1, __int_as_float(i1), v2, 0.f);
    }
}

// -------- merge 8 C-tiles, write approx argmax, flag small-gap rows --------

__global__ __launch_bounds__(256) void ve_flag8(const float4* __restrict__ part,
        unsigned int* __restrict__ wout, unsigned int* __restrict__ rlist,
        unsigned int* __restrict__ cnts) {
    int r = blockIdx.x * 256 + threadIdx.x;
#pragma unroll
    for (int m = 0; m < M_N; ++m) {
        float4 o = part[((size_t)m * B_N + r) * 8 + 0];
        float v1 = o.x; int i1 = __float_as_int(o.y); float v2 = o.z;
#pragma unroll
        for (int t = 1; t < 8; ++t) {
            float4 q = part[((size_t)m * B_N + r) * 8 + t];
            if (q.x > v1) {
                v2 = fmaxf(v1, fmaxf(q.z, v2));
                v1 = q.x; i1 = __float_as_int(q.y);
            } else {
                v2 = fmaxf(v2, q.x);
            }
        }
        wout[m * B_N + r] = (unsigned)i1;
        if (v1 - v2 <= GAP_EPS) {
            unsigned pos = atomicAdd(&cnts[m], 1u);
            rlist[m * B_N + pos] = (unsigned)r;
        }
    }
}

// -------- grouped exact pass (32 rows/block): fp32 serial-k FMA, numpy-matching --------

__global__ __launch_bounds__(256) void ve_exact_g(
        const float* __restrict__ x, const float* __restrict__ W,
        const float* __restrict__ bias, const unsigned int* __restrict__ rlist,
        const unsigned int* __restrict__ cnts, float2* __restrict__ part2) {
    __shared__ float xs[32][33];
    __shared__ float wsm[32][128];
    __shared__ int rg[32];
    const int ct = blockIdx.x, m = blockIdx.z;
    const int tid = threadIdx.x;
    const int tx = tid & 15, ty = tid >> 4;
    const int c0 = ct * 128;
    const unsigned nm = cnts[m];

    for (unsigned rb = blockIdx.y; rb * 32 < nm; rb += gridDim.y) {
        __syncthreads();
        if (tid < 32) {
            unsigned idx = rb * 32 + tid;
            rg[tid] = (idx < nm) ? (int)rlist[m * B_N + idx] : 0;
        }
        __syncthreads();

        float acc[2][8];
#pragma unroll
        for (int i = 0; i < 2; i++)
#pragma unroll
            for (int j = 0; j < 8; j++) acc[i][j] = 0.f;

        for (int kt = 0; kt < D_K; kt += 32) {
            {
                int row = tid >> 3, kq = tid & 7;
                float4 v = *reinterpret_cast<const float4*>(
                        x + (size_t)rg[row] * D_K + kt + kq * 4);
                int kk = kq * 4;
                xs[kk + 0][row] = v.x; xs[kk + 1][row] = v.y;
                xs[kk + 2][row] = v.z; xs[kk + 3][row] = v.w;
            }
#pragma unroll
            for (int i = 0; i < 4; i++) {
                int li = tid + i * 256;
                int kk = li >> 5, cq = li & 31;
                int c = c0 + cq * 4;
                const float* p = W + ((size_t)(m * D_K + kt + kk)) * C_N + c;
                float4 v;
                if (c + 3 < C_N) v = *reinterpret_cast<const float4*>(p);
                else {
                    v.x = (c + 0 < C_N) ? p[0] : 0.f; v.y = (c + 1 < C_N) ? p[1] : 0.f;
                    v.z = (c + 2 < C_N) ? p[2] : 0.f; v.w = (c + 3 < C_N) ? p[3] : 0.f;
                }
                wsm[kk][cq * 4 + 0] = v.x; wsm[kk][cq * 4 + 1] = v.y;
                wsm[kk][cq * 4 + 2] = v.z; wsm[kk][cq * 4 + 3] = v.w;
            }
            __syncthreads();
            for (int kk = 0; kk < 32; kk++) {
                float a0 = xs[kk][ty], a1 = xs[kk][ty + 16];
                float bb[8];
#pragma unroll
                for (int j = 0; j < 8; j++) bb[j] = wsm[kk][tx + j * 16];
#pragma unroll
                for (int j = 0; j < 8; j++) {
                    acc[0][j] += a0 * bb[j];
                    acc[1][j] += a1 * bb[j];
                }
            }
            __syncthreads();
        }

        const float NEG_INF = -__builtin_huge_valf();
        float bv[8]; int cv[8];
#pragma unroll
        for (int j = 0; j < 8; j++) {
            int c = c0 + tx + j * 16;
            cv[j] = c;
            bv[j] = (c < C_N) ? bias[m * C_N + c] : 0.f;
        }
#pragma unroll
        for (int i = 0; i < 2; i++) {
            float best = NEG_INF; int bidx = 0x7fffffff;
#pragma unroll
            for (int j = 0; j < 8; j++) {
                int c = cv[j];
                float v = (c < C_N) ? (acc[i][j] + bv[j]) : NEG_INF;
                if (v > best || (v == best && c < bidx)) { best = v; bidx = c; }
            }
#pragma unroll
            for (int mask = 1; mask < 16; mask <<= 1) {
                float ov = __shfl_xor(best, mask);
                int oi = __shfl_xor(bidx, mask);
                if (ov > best || (ov == best && oi < bidx)) { best = ov; bidx = oi; }
            }
            unsigned slot = rb * 32 + ty + i * 16;
            if (tx == 0 && slot < nm)
                part2[((size_t)m * B_N + slot) * 8 + ct] = make_float2(best, __int_as_float(bidx));
        }
    }
}

// merge exact per-ct partials -> final argmax for flagged rows
__global__ __launch_bounds__(256) void ve_merge_x(const float2* __restrict__ part2,
        const unsigned int* __restrict__ rlist, const unsigned int* __restrict__ cnts,
        unsigned int* __restrict__ wout) {
    int gid = blockIdx.x * 256 + threadIdx.x;
    int m = gid >> 14, s = gid & (B_N - 1);
    if (s < (int)cnts[m]) {
        const float NEG_INF = -__builtin_huge_valf();
        float best = NEG_INF; int bidx = 0x7fffffff;
#pragma unroll
        for (int ctt = 0; ctt < 8; ctt++) {
            float2 p = part2[((size_t)m * B_N + s) * 8 + ctt];
            int oi = __float_as_int(p.y);
            if (p.x > best || (p.x == best && oi < bidx)) { best = p.x; bidx = oi; }
        }
        wout[m * B_N + rlist[m * B_N + s]] = (unsigned)bidx;
    }
}

// -------- fused zero + weighted vote: block owns 256 rows --------
__global__ __launch_bounds__(256) void ve_votef(const unsigned int* __restrict__ wout,
        const float* __restrict__ coefs, float* __restrict__ out) {
    const int tid = threadIdx.x;
    float4* po = reinterpret_cast<float4*>(out) + (size_t)blockIdx.x * 64000;
    const float4 z = make_float4(0.f, 0.f, 0.f, 0.f);
    for (int i = 0; i < 250; ++i) po[i * 256 + tid] = z;
    __syncthreads();
    int r = blockIdx.x * 256 + tid;
#pragma unroll
    for (int m = 0; m < M_N; ++m)
        out[(size_t)r * C_N + wout[m * B_N + r]] += coefs[m] * 0.125f;
}

// ================= fallback: proven round-1 fp32 path =================

#define TM 128
#define TN 128
#define TK 32
#define CT 8

__global__ __launch_bounds__(256) void ve_zero_out(float* __restrict__ out, int n4) {
    int i = blockIdx.x * blockDim.x + threadIdx.x;
    const float4 z = make_float4(0.f, 0.f, 0.f, 0.f);
    for (; i < n4; i += gridDim.x * blockDim.x)
        reinterpret_cast<float4*>(out)[i] = z;
}

__global__ __launch_bounds__(256) void ve_gemm_argmax_fb(
        const float* __restrict__ x, const float* __restrict__ W,
        const float* __restrict__ bias, float2* __restrict__ part) {
    __shared__ float xs[TK][TM + 1];
    __shared__ float ws[TK][TN];
    const int ct = blockIdx.x, rt = blockIdx.y, m = blockIdx.z;
    const int tid = threadIdx.x;
    const int tx = tid & 15, ty = tid >> 4;
    const int r0 = rt * TM, c0 = ct * TN;
    float acc[8][8];
#pragma unroll
    for (int i = 0; i < 8; i++)
#pragma unroll
        for (int j = 0; j < 8; j++) acc[i][j] = 0.f;
    const float* xbase = x + (size_t)r0 * D_K;
    for (int kt = 0; kt < D_K; kt += TK) {
#pragma unroll
        for (int i = 0; i < 4; i++) {
            int li = tid + i * 256;
            int row = li >> 3, kq = li & 7;
            float4 v = *reinterpret_cast<const float4*>(xbase + (size_t)row * D_K + kt + kq * 4);
            int kk = kq * 4;
            xs[kk + 0][row] = v.x; xs[kk + 1][row] = v.y;
            xs[kk + 2][row] = v.z; xs[kk + 3][row] = v.w;
        }
#pragma unroll
        for (int i = 0; i < 4; i++) {
            int li = tid + i * 256;
            int kk = li >> 5, cq = li & 31;
            int c = c0 + cq * 4;
            const float* p = W + ((size_t)(m * D_K + kt + kk)) * C_N + c;
            float4 v;
            if (c + 3 < C_N) v = *reinterpret_cast<const float4*>(p);
            else {
                v.x = (c + 0 < C_N) ? p[0] : 0.f; v.y = (c + 1 < C_N) ? p[1] : 0.f;
                v.z = (c + 2 < C_N) ? p[2] : 0.f; v.w = (c + 3 < C_N) ? p[3] : 0.f;
            }
            ws[kk][cq * 4 + 0] = v.x; ws[kk][cq * 4 + 1] = v.y;
            ws[kk][cq * 4 + 2] = v.z; ws[kk][cq * 4 + 3] = v.w;
        }
        __syncthreads();
        for (int kk = 0; kk < TK; kk++) {
            float a[8], bb[8];
#pragma unroll
            for (int i = 0; i < 8; i++) a[i] = xs[kk][ty + i * 16];
#pragma unroll
            for (int j = 0; j < 8; j++) bb[j] = ws[kk][tx + j * 16];
#pragma unroll
            for (int i = 0; i < 8; i++)
#pragma unroll
                for (int j = 0; j < 8; j++) acc[i][j] += a[i] * bb[j];
        }
        __syncthreads();
    }
    const float NEG_INF = -__builtin_huge_valf();
    float bv[8]; int cv[8];
#pragma unroll
    for (int j = 0; j < 8; j++) {
        int c = c0 + tx + j * 16;
        cv[j] = c;
        bv[j] = (c < C_N) ? bias[m * C_N + c] : 0.f;
    }
#pragma unroll
    for (int i = 0; i < 8; i++) {
        int r = r0 + ty + i * 16;
        float best = NEG_INF; int bidx = 0x7fffffff;
#pragma unroll
        for (int j = 0; j < 8; j++) {
            int c = cv[j];
            float v = (c < C_N) ? (acc[i][j] + bv[j]) : NEG_INF;
            if (v > best || (v == best && c < bidx)) { best = v; bidx = c; }
        }
#pragma unroll
        for (int mask = 1; mask < 16; mask <<= 1) {
            float ov = __shfl_xor(best, mask);
            int oi = __shfl_xor(bidx, mask);
            if (ov > best || (ov == best && oi < bidx)) { best = ov; bidx = oi; }
        }
        if (tx == 0) part[((size_t)m * B_N + r) * CT + ct] = make_float2(best, __int_as_float(bidx));
    }
}

__global__ __launch_bounds__(256) void ve_vote_fb(const float2* __restrict__ part,
        const float* __restrict__ coefs, float* __restrict__ out) {
    int r = blockIdx.x * blockDim.x + threadIdx.x;
    if (r >= B_N) return;
    const float NEG_INF = -__builtin_huge_valf();
#pragma unroll
    for (int m = 0; m < M_N; m++) {
        float best = NEG_INF; int bidx = 0x7fffffff;
#pragma unroll
        for (int ctt = 0; ctt < CT; ctt++) {
            float2 p = part[((size_t)m * B_N + r) * CT + ctt];
            int oi = __float_as_int(p.y);
            if (p.x > best || (p.x == best && oi < bidx)) { best = p.x; bidx = oi; }
        }
        out[(size_t)r * C_N + bidx] += coefs[m] * 0.125f;
    }
}

// ================= launcher =================

extern "C" void kernel_launch(void* const* d_in, const int* in_sizes, int n_in,
                              void* d_out, int out_size, void* d_ws, size_t ws_size,
                              hipStream_t stream) {
    const float* x     = (const float*)d_in[0];
    const float* W     = (const float*)d_in[1];
    const float* bias  = (const float*)d_in[2];
    const float* coefs = (const float*)d_in[3];
    float* out = (float*)d_out;

    const size_t NEED = (57ull << 20) + 4096;
    if (ws_size >= NEED) {
        char* ws = (char*)d_ws;
        unsigned short* Xf    = (unsigned short*)(ws);                   // 16 MiB
        unsigned short* WT16  = (unsigned short*)(ws + (16ull << 20));   //  8 MiB
        float4*         part  = (float4*)(ws + (24ull << 20));           // 16 MiB
        float2*         part2 = (float2*)(ws + (40ull << 20));           //  8 MiB
        unsigned int*   wout  = (unsigned int*)(ws + (48ull << 20));     // 512 KiB
        unsigned int*   rlist = (unsigned int*)(ws + (48ull << 20) + (512ull << 10)); // 512 KiB
        unsigned int*   cnts  = (unsigned int*)(ws + (49ull << 20));     // 32 B

        ve_conv<<<9216, 256, 0, stream>>>(x, W, Xf, WT16, cnts);
        ve_gemm16e<<<8192, 512, 0, stream>>>(Xf, WT16, bias, part);
        ve_flag8<<<64, 256, 0, stream>>>(part, wout, rlist, cnts);
        ve_exact_g<<<dim3(8, 16, 8), 256, 0, stream>>>(x, W, bias, rlist, cnts, part2);
        ve_merge_x<<<512, 256, 0, stream>>>(part2, rlist, cnts, wout);
        ve_votef<<<64, 256, 0, stream>>>(wout, coefs, out);
    } else {
        float2* partf = (float2*)d_ws;
        ve_zero_out<<<2048, 256, 0, stream>>>(out, B_N * C_N / 4);
        dim3 grid(CT, B_N / TM, M_N);
        ve_gemm_argmax_fb<<<grid, 256, 0, stream>>>(x, W, bias, partf);
        ve_vote_fb<<<(B_N + 255) / 256, 256, 0, stream>>>(partf, coefs, out);
    }
}

// Round 13
// 416.638 us; speedup vs baseline: 1.4633x; 1.4633x over previous
//
#include <hip/hip_runtime.h>

#define B_N 16384
#define D_K 512
#define C_N 1000
#define CP 1024
#define M_N 8
#define GAP_EPS 1e-3f

typedef __attribute__((ext_vector_type(8))) _Float16 f16x8;
typedef __attribute__((ext_vector_type(4))) float f32x4;

typedef const __attribute__((address_space(1))) unsigned int* gptr_t;
typedef __attribute__((address_space(3))) unsigned int* lptr_t;

__device__ __forceinline__ void gload16(const void* g, void* l) {
    __builtin_amdgcn_global_load_lds((gptr_t)g, (lptr_t)l, 16, 0, 0);
}

__device__ __forceinline__ unsigned short h16(float f) {
    _Float16 h = (_Float16)f;   // v_cvt_f16_f32, RTN
    return *(unsigned short*)&h;
}

// ---------------- fused conversion kernel (round-12-verified) ----------------

__global__ __launch_bounds__(256) void ve_conv(const float* __restrict__ x,
        const float* __restrict__ W, unsigned short* __restrict__ xf,
        unsigned short* __restrict__ wt, unsigned int* __restrict__ cnts) {
    const int tid = threadIdx.x;
    if (blockIdx.x < 8192) {
        int i = blockIdx.x * 256 + tid;
        if (blockIdx.x == 0 && tid < M_N) cnts[tid] = 0u;
        float4 v = reinterpret_cast<const float4*>(x)[i];
        ushort4 h;
        h.x = h16(v.x); h.y = h16(v.y); h.z = h16(v.z); h.w = h16(v.w);
        reinterpret_cast<ushort4*>(xf)[i] = h;
    } else {
        __shared__ float t[64][65];
        const int b = blockIdx.x - 8192;
        const int c0 = (b & 15) * 64, k0 = ((b >> 4) & 7) * 64, m = b >> 7;
#pragma unroll
        for (int p = 0; p < 16; ++p) {
            int idx = p * 256 + tid;
            int kk = idx >> 6, cc = idx & 63;
            int c = c0 + cc;
            t[kk][cc] = (c < C_N) ? W[((size_t)m * D_K + k0 + kk) * C_N + c] : 0.f;
        }
        __syncthreads();
#pragma unroll
        for (int p = 0; p < 4; ++p) {
            int idx = p * 256 + tid;
            int cc = idx >> 4, kq = idx & 15;
            ushort4 h;
            h.x = h16(t[kq * 4 + 0][cc]); h.y = h16(t[kq * 4 + 1][cc]);
            h.z = h16(t[kq * 4 + 2][cc]); h.w = h16(t[kq * 4 + 3][cc]);
            size_t o = ((size_t)m * CP + c0 + cc) * D_K + k0 + kq * 4;
            *reinterpret_cast<ushort4*>(wt + o) = h;
        }
    }
}

// ------- fp16 MFMA GEMM, 128x128 tile, 4 waves, BK=64, double-buffered -------
// Round-9-verified LDS layout/swizzle per 16KB tile buffer; NOW 2 buffers.
// Per iter: issue stage(t+1) into buf^1 FIRST, then frag-read + 32 MFMA from
// buf, then ONE __syncthreads (drains vmcnt0+lgkm0) serving RAW(t+1)+WAR(t).
// Stage latency hides under compute. Grid x=ct (innermost) so the 8 blocks
// sharing an A row-panel are dispatch-adjacent -> A L2-resident.

__global__ __launch_bounds__(256, 2) void ve_gemm16d(
        const unsigned short* __restrict__ Xf, const unsigned short* __restrict__ WT,
        const float* __restrict__ bias, float4* __restrict__ part) {
    __shared__ unsigned short At[16384];   // 32 KB: 2 bufs x [subk][128r x 32k]
    __shared__ unsigned short Bt[16384];   // 32 KB

    const int tid = threadIdx.x;
    const int l = tid & 63, w = tid >> 6;
    const int wr = w >> 1, wc = w & 1;        // 2x2 waves; per-wave C = 64x64
    const int l15 = l & 15, kg = l >> 4;
    const int ct = blockIdx.x, rt = blockIdx.y, mb = blockIdx.z;
    const int r0 = rt * 128, c0 = ct * 128;

    // staging lane constants (round-9-verified inverse swizzle)
    const int lhi = l >> 3, llo = l & 7;
    const int s3g = llo ^ lhi;
    const int srow16 = (lhi << 1) | (s3g >> 2);
    const int kgs = (s3g & 3) * 8;            // shorts

    const unsigned short* xA0 = Xf + (size_t)(r0 +      w * 16 + srow16) * D_K + kgs;
    const unsigned short* xA1 = Xf + (size_t)(r0 + 64 + w * 16 + srow16) * D_K + kgs;
    const unsigned short* xB0 = WT + (size_t)(mb * CP + c0 +      w * 16 + srow16) * D_K + kgs;
    const unsigned short* xB1 = WT + (size_t)(mb * CP + c0 + 64 + w * 16 + srow16) * D_K + kgs;

    auto stage = [&](int t, int buf) {
        unsigned short* A = At + buf * 8192;
        unsigned short* B = Bt + buf * 8192;
        gload16(xA0 + t * 64,      A + tid * 8);           // subk0 rows 0-63
        gload16(xA1 + t * 64,      A + 2048 + tid * 8);    // subk0 rows 64-127
        gload16(xA0 + t * 64 + 32, A + 4096 + tid * 8);    // subk1 rows 0-63
        gload16(xA1 + t * 64 + 32, A + 6144 + tid * 8);    // subk1 rows 64-127
        gload16(xB0 + t * 64,      B + tid * 8);
        gload16(xB1 + t * 64,      B + 2048 + tid * 8);
        gload16(xB0 + t * 64 + 32, B + 4096 + tid * 8);
        gload16(xB1 + t * 64 + 32, B + 6144 + tid * 8);
    };

    // fragment read byte-offsets within buffer 0 (round-9-verified formula)
    auto ldsoff = [&](int row, int kc) {
        return (row >> 1) * 64 + (((((row & 1) << 2) | kc) ^ ((row >> 1) & 7)) * 8);
    };
    const char* aP[4]; const char* bP[4];
#pragma unroll
    for (int i = 0; i < 4; ++i) {
        aP[i] = (const char*)At + 2 * ldsoff(wr * 64 + i * 16 + l15, kg);
        bP[i] = (const char*)Bt + 2 * ldsoff(wc * 64 + i * 16 + l15, kg);
    }

    f32x4 acc[4][4];
#pragma unroll
    for (int i = 0; i < 4; ++i)
#pragma unroll
        for (int j = 0; j < 4; ++j) acc[i][j] = (f32x4){0.f, 0.f, 0.f, 0.f};

    // prologue: stage tile 0 -> buf 0; drain; barrier.
    stage(0, 0);
    __syncthreads();

#pragma unroll
    for (int t = 0; t < 8; ++t) {
        const int cur = (t & 1) * 16384;   // byte offset of current buffer
        if (t < 7) stage(t + 1, (t & 1) ^ 1);   // prefetch while computing

        f16x8 af[4], bf[4];
        // ---- subk 0 ----
#pragma unroll
        for (int i = 0; i < 4; ++i) af[i] = *reinterpret_cast<const f16x8*>(aP[i] + cur);
#pragma unroll
        for (int j = 0; j < 4; ++j) bf[j] = *reinterpret_cast<const f16x8*>(bP[j] + cur);
#pragma unroll
        for (int i = 0; i < 4; ++i)
#pragma unroll
            for (int j = 0; j < 4; ++j)
                acc[i][j] = __builtin_amdgcn_mfma_f32_16x16x32_f16(af[i], bf[j], acc[i][j], 0, 0, 0);
        // ---- subk 1 ----
#pragma unroll
        for (int i = 0; i < 4; ++i) af[i] = *reinterpret_cast<const f16x8*>(aP[i] + cur + 8192);
#pragma unroll
        for (int j = 0; j < 4; ++j) bf[j] = *reinterpret_cast<const f16x8*>(bP[j] + cur + 8192);
#pragma unroll
        for (int i = 0; i < 4; ++i)
#pragma unroll
            for (int j = 0; j < 4; ++j)
                acc[i][j] = __builtin_amdgcn_mfma_f32_16x16x32_f16(af[i], bf[j], acc[i][j], 0, 0, 0);

        // ONE barrier: drains vmcnt(0) (stage t+1 landed) + lgkmcnt(0)
        // (this iter's frag reads done) -> RAW for t+1, WAR for t+2's buf.
        __syncthreads();
    }

    // ---------------- epilogue: bias + cheap running top-2 ----------------
    float4 (*wtop)[2] = reinterpret_cast<float4(*)[2]>(At);   // overlays dead At

    float bv[4]; int cg[4];
#pragma unroll
    for (int j = 0; j < 4; ++j) {
        int c = c0 + wc * 64 + j * 16 + l15;
        cg[j] = c;
        bv[j] = (c < C_N) ? bias[mb * C_N + c] : -1e30f;
    }
#pragma unroll
    for (int i = 0; i < 4; ++i) {
#pragma unroll
        for (int reg = 0; reg < 4; ++reg) {
            float v1 = acc[i][0][reg] + bv[0]; int i1 = cg[0];
            float v2 = -1e30f;
#pragma unroll
            for (int j = 1; j < 4; ++j) {
                float v = acc[i][j][reg] + bv[j];
                float mn = fminf(v, v1);
                v2 = fmaxf(v2, mn);
                i1 = (v > v1) ? cg[j] : i1;
                v1 = fmaxf(v1, v);
            }
#pragma unroll
            for (int mask = 1; mask < 16; mask <<= 1) {
                float ov1 = __shfl_xor(v1, mask);
                int   oi1 = __shfl_xor(i1, mask);
                float ov2 = __shfl_xor(v2, mask);
                float mn = fminf(v1, ov1);
                v2 = fmaxf(fmaxf(v2, ov2), mn);
                i1 = (ov1 > v1) ? oi1 : i1;
                v1 = fmaxf(v1, ov1);
            }
            if (l15 == 0) {
                int row = wr * 64 + i * 16 + (l >> 4) * 4 + reg;
                wtop[row][wc] = make_float4(v1, __int_as_float(i1), v2, 0.f);
            }
        }
    }
    __syncthreads();
    if (tid < 128) {
        float4 a = wtop[tid][0], b = wtop[tid][1];
        float v1, v2; int i1;
        if (b.x > a.x) {
            v1 = b.x; i1 = __float_as_int(b.y);
            v2 = fmaxf(a.x, b.z);
        } else {
            v1 = a.x; i1 = __float_as_int(a.y);
            v2 = fmaxf(b.x, a.z);
        }
        part[((size_t)mb * B_N + r0 + tid) * 8 + ct] =
            make_float4(v1, __int_as_float(i1), v2, 0.f);
    }
}

// -------- merge 8 C-tiles, write approx argmax, flag small-gap rows --------

__global__ __launch_bounds__(256) void ve_flag8(const float4* __restrict__ part,
        unsigned int* __restrict__ wout, unsigned int* __restrict__ rlist,
        unsigned int* __restrict__ cnts) {
    int r = blockIdx.x * 256 + threadIdx.x;
#pragma unroll
    for (int m = 0; m < M_N; ++m) {
        float4 o = part[((size_t)m * B_N + r) * 8 + 0];
        float v1 = o.x; int i1 = __float_as_int(o.y); float v2 = o.z;
#pragma unroll
        for (int t = 1; t < 8; ++t) {
            float4 q = part[((size_t)m * B_N + r) * 8 + t];
            if (q.x > v1) {
                v2 = fmaxf(v1, fmaxf(q.z, v2));
                v1 = q.x; i1 = __float_as_int(q.y);
            } else {
                v2 = fmaxf(v2, q.x);
            }
        }
        wout[m * B_N + r] = (unsigned)i1;
        if (v1 - v2 <= GAP_EPS) {
            unsigned pos = atomicAdd(&cnts[m], 1u);
            rlist[m * B_N + pos] = (unsigned)r;
        }
    }
}

// -------- grouped exact pass (round-8-verified, 128 rows/block) --------

__global__ __launch_bounds__(256) void ve_exact_g(
        const float* __restrict__ x, const float* __restrict__ W,
        const float* __restrict__ bias, const unsigned int* __restrict__ rlist,
        const unsigned int* __restrict__ cnts, float2* __restrict__ part2) {
    __shared__ float xs[32][129];
    __shared__ float wsm[32][128];
    __shared__ int rg[128];
    const int ct = blockIdx.x, m = blockIdx.z;
    const int tid = threadIdx.x;
    const int tx = tid & 15, ty = tid >> 4;
    const int c0 = ct * 128;
    const unsigned nm = cnts[m];

    for (unsigned rb = blockIdx.y; rb * 128 < nm; rb += gridDim.y) {
        __syncthreads();
        if (tid < 128) {
            unsigned idx = rb * 128 + tid;
            rg[tid] = (idx < nm) ? (int)rlist[m * B_N + idx] : 0;
        }
        __syncthreads();

        float acc[8][8];
#pragma unroll
        for (int i = 0; i < 8; i++)
#pragma unroll
            for (int j = 0; j < 8; j++) acc[i][j] = 0.f;

        for (int kt = 0; kt < D_K; kt += 32) {
#pragma unroll
            for (int i = 0; i < 4; i++) {
                int li = tid + i * 256;
                int row = li >> 3, kq = li & 7;
                float4 v = *reinterpret_cast<const float4*>(
                        x + (size_t)rg[row] * D_K + kt + kq * 4);
                int kk = kq * 4;
                xs[kk + 0][row] = v.x; xs[kk + 1][row] = v.y;
                xs[kk + 2][row] = v.z; xs[kk + 3][row] = v.w;
            }
#pragma unroll
            for (int i = 0; i < 4; i++) {
                int li = tid + i * 256;
                int kk = li >> 5, cq = li & 31;
                int c = c0 + cq * 4;
                const float* p = W + ((size_t)(m * D_K + kt + kk)) * C_N + c;
                float4 v;
                if (c + 3 < C_N) v = *reinterpret_cast<const float4*>(p);
                else {
                    v.x = (c + 0 < C_N) ? p[0] : 0.f; v.y = (c + 1 < C_N) ? p[1] : 0.f;
                    v.z = (c + 2 < C_N) ? p[2] : 0.f; v.w = (c + 3 < C_N) ? p[3] : 0.f;
                }
                wsm[kk][cq * 4 + 0] = v.x; wsm[kk][cq * 4 + 1] = v.y;
                wsm[kk][cq * 4 + 2] = v.z; wsm[kk][cq * 4 + 3] = v.w;
            }
            __syncthreads();
            for (int kk = 0; kk < 32; kk++) {
                float a[8], bb[8];
#pragma unroll
                for (int i = 0; i < 8; i++) a[i] = xs[kk][ty + i * 16];
#pragma unroll
                for (int j = 0; j < 8; j++) bb[j] = wsm[kk][tx + j * 16];
#pragma unroll
                for (int i = 0; i < 8; i++)
#pragma unroll
                    for (int j = 0; j < 8; j++) acc[i][j] += a[i] * bb[j];
            }
            __syncthreads();
        }

        const float NEG_INF = -__builtin_huge_valf();
        float bv[8]; int cv[8];
#pragma unroll
        for (int j = 0; j < 8; j++) {
            int c = c0 + tx + j * 16;
            cv[j] = c;
            bv[j] = (c < C_N) ? bias[m * C_N + c] : 0.f;
        }
#pragma unroll
        for (int i = 0; i < 8; i++) {
            float best = NEG_INF; int bidx = 0x7fffffff;
#pragma unroll
            for (int j = 0; j < 8; j++) {
                int c = cv[j];
                float v = (c < C_N) ? (acc[i][j] + bv[j]) : NEG_INF;
                if (v > best || (v == best && c < bidx)) { best = v; bidx = c; }
            }
#pragma unroll
            for (int mask = 1; mask < 16; mask <<= 1) {
                float ov = __shfl_xor(best, mask);
                int oi = __shfl_xor(bidx, mask);
                if (ov > best || (ov == best && oi < bidx)) { best = ov; bidx = oi; }
            }
            unsigned slot = rb * 128 + ty + i * 16;
            if (tx == 0 && slot < nm)
                part2[((size_t)m * B_N + slot) * 8 + ct] = make_float2(best, __int_as_float(bidx));
        }
    }
}

// merge exact per-ct partials -> final argmax for flagged rows
__global__ __launch_bounds__(256) void ve_merge_x(const float2* __restrict__ part2,
        const unsigned int* __restrict__ rlist, const unsigned int* __restrict__ cnts,
        unsigned int* __restrict__ wout) {
    int gid = blockIdx.x * 256 + threadIdx.x;
    int m = gid >> 14, s = gid & (B_N - 1);
    if (s < (int)cnts[m]) {
        const float NEG_INF = -__builtin_huge_valf();
        float best = NEG_INF; int bidx = 0x7fffffff;
#pragma unroll
        for (int ctt = 0; ctt < 8; ctt++) {
            float2 p = part2[((size_t)m * B_N + s) * 8 + ctt];
            int oi = __float_as_int(p.y);
            if (p.x > best || (p.x == best && oi < bidx)) { best = p.x; bidx = oi; }
        }
        wout[m * B_N + rlist[m * B_N + s]] = (unsigned)bidx;
    }
}

// -------- fused zero + weighted vote: block owns 256 rows --------
__global__ __launch_bounds__(256) void ve_votef(const unsigned int* __restrict__ wout,
        const float* __restrict__ coefs, float* __restrict__ out) {
    const int tid = threadIdx.x;
    float4* po = reinterpret_cast<float4*>(out) + (size_t)blockIdx.x * 64000;
    const float4 z = make_float4(0.f, 0.f, 0.f, 0.f);
    for (int i = 0; i < 250; ++i) po[i * 256 + tid] = z;
    __syncthreads();
    int r = blockIdx.x * 256 + tid;
#pragma unroll
    for (int m = 0; m < M_N; ++m)
        out[(size_t)r * C_N + wout[m * B_N + r]] += coefs[m] * 0.125f;
}

// ================= fallback: proven round-1 fp32 path =================

#define TM 128
#define TN 128
#define TK 32
#define CT 8

__global__ __launch_bounds__(256) void ve_zero_out(float* __restrict__ out, int n4) {
    int i = blockIdx.x * blockDim.x + threadIdx.x;
    const float4 z = make_float4(0.f, 0.f, 0.f, 0.f);
    for (; i < n4; i += gridDim.x * blockDim.x)
        reinterpret_cast<float4*>(out)[i] = z;
}

__global__ __launch_bounds__(256) void ve_gemm_argmax_fb(
        const float* __restrict__ x, const float* __restrict__ W,
        const float* __restrict__ bias, float2* __restrict__ part) {
    __shared__ float xs[TK][TM + 1];
    __shared__ float ws[TK][TN];
    const int ct = blockIdx.x, rt = blockIdx.y, m = blockIdx.z;
    const int tid = threadIdx.x;
    const int tx = tid & 15, ty = tid >> 4;
    const int r0 = rt * TM, c0 = ct * TN;
    float acc[8][8];
#pragma unroll
    for (int i = 0; i < 8; i++)
#pragma unroll
        for (int j = 0; j < 8; j++) acc[i][j] = 0.f;
    const float* xbase = x + (size_t)r0 * D_K;
    for (int kt = 0; kt < D_K; kt += TK) {
#pragma unroll
        for (int i = 0; i < 4; i++) {
            int li = tid + i * 256;
            int row = li >> 3, kq = li & 7;
            float4 v = *reinterpret_cast<const float4*>(xbase + (size_t)row * D_K + kt + kq * 4);
            int kk = kq * 4;
            xs[kk + 0][row] = v.x; xs[kk + 1][row] = v.y;
            xs[kk + 2][row] = v.z; xs[kk + 3][row] = v.w;
        }
#pragma unroll
        for (int i = 0; i < 4; i++) {
            int li = tid + i * 256;
            int kk = li >> 5, cq = li & 31;
            int c = c0 + cq * 4;
            const float* p = W + ((size_t)(m * D_K + kt + kk)) * C_N + c;
            float4 v;
            if (c + 3 < C_N) v = *reinterpret_cast<const float4*>(p);
            else {
                v.x = (c + 0 < C_N) ? p[0] : 0.f; v.y = (c + 1 < C_N) ? p[1] : 0.f;
                v.z = (c + 2 < C_N) ? p[2] : 0.f; v.w = (c + 3 < C_N) ? p[3] : 0.f;
            }
            ws[kk][cq * 4 + 0] = v.x; ws[kk][cq * 4 + 1] = v.y;
            ws[kk][cq * 4 + 2] = v.z; ws[kk][cq * 4 + 3] = v.w;
        }
        __syncthreads();
        for (int kk = 0; kk < TK; kk++) {
            float a[8], bb[8];
#pragma unroll
            for (int i = 0; i < 8; i++) a[i] = xs[kk][ty + i * 16];
#pragma unroll
            for (int j = 0; j < 8; j++) bb[j] = ws[kk][tx + j * 16];
#pragma unroll
            for (int i = 0; i < 8; i++)
#pragma unroll
                for (int j = 0; j < 8; j++) acc[i][j] += a[i] * bb[j];
        }
        __syncthreads();
    }
    const float NEG_INF = -__builtin_huge_valf();
    float bv[8]; int cv[8];
#pragma unroll
    for (int j = 0; j < 8; j++) {
        int c = c0 + tx + j * 16;
        cv[j] = c;
        bv[j] = (c < C_N) ? bias[m * C_N + c] : 0.f;
    }
#pragma unroll
    for (int i = 0; i < 8; i++) {
        int r = r0 + ty + i * 16;
        float best = NEG_INF; int bidx = 0x7fffffff;
#pragma unroll
        for (int j = 0; j < 8; j++) {
            int c = cv[j];
            float v = (c < C_N) ? (acc[i][j] + bv[j]) : NEG_INF;
            if (v > best || (v == best && c < bidx)) { best = v; bidx = c; }
        }
#pragma unroll
        for (int mask = 1; mask < 16; mask <<= 1) {
            float ov = __shfl_xor(best, mask);
            int oi = __shfl_xor(bidx, mask);
            if (ov > best || (ov == best && oi < bidx)) { best = ov; bidx = oi; }
        }
        if (tx == 0) part[((size_t)m * B_N + r) * CT + ct] = make_float2(best, __int_as_float(bidx));
    }
}

__global__ __launch_bounds__(256) void ve_vote_fb(const float2* __restrict__ part,
        const float* __restrict__ coefs, float* __restrict__ out) {
    int r = blockIdx.x * blockDim.x + threadIdx.x;
    if (r >= B_N) return;
    const float NEG_INF = -__builtin_huge_valf();
#pragma unroll
    for (int m = 0; m < M_N; m++) {
        float best = NEG_INF; int bidx = 0x7fffffff;
#pragma unroll
        for (int ctt = 0; ctt < CT; ctt++) {
            float2 p = part[((size_t)m * B_N + r) * CT + ctt];
            int oi = __float_as_int(p.y);
            if (p.x > best || (p.x == best && oi < bidx)) { best = p.x; bidx = oi; }
        }
        out[(size_t)r * C_N + bidx] += coefs[m] * 0.125f;
    }
}

// ================= launcher =================

extern "C" void kernel_launch(void* const* d_in, const int* in_sizes, int n_in,
                              void* d_out, int out_size, void* d_ws, size_t ws_size,
                              hipStream_t stream) {
    const float* x     = (const float*)d_in[0];
    const float* W     = (const float*)d_in[1];
    const float* bias  = (const float*)d_in[2];
    const float* coefs = (const float*)d_in[3];
    float* out = (float*)d_out;

    const size_t NEED = (57ull << 20) + 4096;
    if (ws_size >= NEED) {
        char* ws = (char*)d_ws;
        unsigned short* Xf    = (unsigned short*)(ws);                   // 16 MiB
        unsigned short* WT16  = (unsigned short*)(ws + (16ull << 20));   //  8 MiB
        float4*         part  = (float4*)(ws + (24ull << 20));           // 16 MiB
        float2*         part2 = (float2*)(ws + (40ull << 20));           //  8 MiB
        unsigned int*   wout  = (unsigned int*)(ws + (48ull << 20));     // 512 KiB
        unsigned int*   rlist = (unsigned int*)(ws + (48ull << 20) + (512ull << 10)); // 512 KiB
        unsigned int*   cnts  = (unsigned int*)(ws + (49ull << 20));     // 32 B

        ve_conv<<<9216, 256, 0, stream>>>(x, W, Xf, WT16, cnts);
        ve_gemm16d<<<dim3(8, 128, 8), 256, 0, stream>>>(Xf, WT16, bias, part);
        ve_flag8<<<64, 256, 0, stream>>>(part, wout, rlist, cnts);
        ve_exact_g<<<dim3(8, 4, 8), 256, 0, stream>>>(x, W, bias, rlist, cnts, part2);
        ve_merge_x<<<512, 256, 0, stream>>>(part2, rlist, cnts, wout);
        ve_votef<<<64, 256, 0, stream>>>(wout, coefs, out);
    } else {
        float2* partf = (float2*)d_ws;
        ve_zero_out<<<2048, 256, 0, stream>>>(out, B_N * C_N / 4);
        dim3 grid(CT, B_N / TM, M_N);
        ve_gemm_argmax_fb<<<grid, 256, 0, stream>>>(x, W, bias, partf);
        ve_vote_fb<<<(B_N + 255) / 256, 256, 0, stream>>>(partf, coefs, out);
    }
}